// Round 3
// baseline (1159.379 us; speedup 1.0000x reference)
//
#include <hip/hip_runtime.h>
#include <hip/hip_bf16.h>
#include <stdint.h>

#define BATCH 64
#define SEQ   2048
#define HID   1024
#define EDIM  2048   // 2*HID

#define BM 64
#define BK 32
#define KSTEPS (EDIM / BK)   // 64
// smem: Bl[2][4][1024][8]sh (128KB) + Al[2][4096B] (8KB) + cov(256B) + sred(2KB)
#define SMEM_BYTES 141568

typedef __bf16 bf16x8 __attribute__((ext_vector_type(8)));
typedef float  f32x16 __attribute__((ext_vector_type(16)));

__device__ __forceinline__ unsigned short f2bf(float x) {
    __hip_bfloat16 h = __float2bfloat16(x);
    return __builtin_bit_cast(unsigned short, h);
}

__device__ __forceinline__ uint4 pack8(float4 f0, float4 f1) {
    uint4 r;
    r.x = (unsigned)f2bf(f0.x) | ((unsigned)f2bf(f0.y) << 16);
    r.y = (unsigned)f2bf(f0.z) | ((unsigned)f2bf(f0.w) << 16);
    r.z = (unsigned)f2bf(f1.x) | ((unsigned)f2bf(f1.y) << 16);
    r.w = (unsigned)f2bf(f1.z) | ((unsigned)f2bf(f1.w) << 16);
    return r;
}

__device__ __forceinline__ void gload16(const void* g, void* l) {
    __builtin_amdgcn_global_load_lds(
        (const __attribute__((address_space(1))) void*)g,
        (__attribute__((address_space(3))) void*)l, 16, 0, 0);
}

// A-tile byte address: row-major 64B rows, XOR swizzle for conflict-free b128 reads
__device__ __forceinline__ int a_addr(int row, int g) {
    return ((row << 6) + (g << 4)) ^ ((row & 7) << 4);
}

// ---------------- prep: W_h (EDIM x HID fp32) -> Wt bf16 in k-granule-major
// layout: element (h, e) at Wt[(e>>3)*8192 + h*8 + (e&7)]
__global__ void wh_transpose_kernel(const float* __restrict__ Wh,
                                    unsigned short* __restrict__ Wt) {
    __shared__ float tile[32][33];
    int bx = blockIdx.x & 63;    // e-tile (2048/32)
    int by = blockIdx.x >> 6;    // h-tile (1024/32)
    int e0 = bx * 32, h0 = by * 32;
    int tx = threadIdx.x & 31, ty = threadIdx.x >> 5;   // 32 x 8
    #pragma unroll
    for (int i = 0; i < 4; ++i)
        tile[ty + 8 * i][tx] = Wh[(size_t)(e0 + ty + 8 * i) * HID + h0 + tx];
    __syncthreads();
    if (ty < 4) {   // 4 granules x 32 h per tile; each thread packs 8 shorts (16B)
        uint4 wv;
        unsigned short* ws = (unsigned short*)&wv;
        #pragma unroll
        for (int j = 0; j < 8; ++j) ws[j] = f2bf(tile[ty * 8 + j][tx]);
        *(uint4*)&Wt[((size_t)(e0 >> 3) + ty) * 8192 + (size_t)(h0 + tx) * 8] = wv;
    }
}

// ---------------- prep: dec_proj = decoder_hidden @ W_d  (fp32, (B,HID))
__global__ void dec_proj_kernel(const float* __restrict__ dec,
                                const float* __restrict__ Wd,
                                float* __restrict__ dp) {
    int gid = blockIdx.x * 256 + threadIdx.x;
    int b = gid >> 10, h = gid & 1023;
    const float* dr = dec + b * HID;
    float acc = 0.f;
    #pragma unroll 4
    for (int k = 0; k < HID; ++k) acc = fmaf(dr[k], Wd[(size_t)k * HID + h], acc);
    dp[gid] = acc;
}

// ---------------- main fused scores kernel: 64 rows x full N=1024, 8 waves
__global__ __launch_bounds__(512, 2) void scores_kernel(
    const float* __restrict__ enc, const float* __restrict__ cov,
    const unsigned short* __restrict__ Wt, const float* __restrict__ dp,
    const float* __restrict__ Wc, const float* __restrict__ vv,
    float* __restrict__ scores)
{
    extern __shared__ char smem[];
    unsigned short* BlS  = (unsigned short*)smem;          // 2 x 32768 shorts (128KB)
    char*  AlB   = smem + 131072;                          // 2 x 4096 B
    float* cov_s = (float*)(smem + 139264);                // 64 floats
    float* sred  = (float*)(smem + 139520);                // 64 x 8 floats

    const int tid  = threadIdx.x;
    const int lane = tid & 63;
    const int wid  = tid >> 6;       // 0..7 : 128-col slice
    const int l31  = lane & 31;
    const int hi   = lane >> 5;

    const int b  = blockIdx.x >> 5;            // 2048 blocks = 64 b x 32 s-tiles
    const int s0 = (blockIdx.x & 31) * BM;

    const float* Abase = enc + (size_t)(b * SEQ + s0) * EDIM;

    // A staging: threads 0..255, one k-granule (8 floats -> 16B bf16) each
    const int arow = tid >> 2;                 // 0..63
    const int ag   = tid & 3;

    f32x16 acc[2][4];
    #pragma unroll
    for (int mi = 0; mi < 2; ++mi)
        #pragma unroll
        for (int nj = 0; nj < 4; ++nj)
            #pragma unroll
            for (int r = 0; r < 16; ++r) acc[mi][nj][r] = 0.f;

    if (tid < BM) cov_s[tid] = cov[b * SEQ + s0 + tid];

    // prologue: stage k-step 0 into buffer 0
    {
        const unsigned short* bsrc = Wt + (size_t)tid * 8;
        unsigned short* bdst = BlS + tid * 8;
        #pragma unroll
        for (int j = 0; j < 8; ++j)
            gload16(bsrc + (size_t)j * 4096, bdst + j * 4096);
        if (tid < 256) {
            const float* ap = Abase + (size_t)arow * EDIM + ag * 8;
            *(uint4*)(AlB + a_addr(arow, ag)) =
                pack8(*(const float4*)ap, *(const float4*)(ap + 4));
        }
    }
    __syncthreads();

    float4 a0n, a1n;
    for (int kk = 0; kk < KSTEPS; ++kk) {
        const int cur = kk & 1, nxt = cur ^ 1;
        const unsigned short* Bcur = BlS + cur * 32768;
        const char* Acur = AlB + cur * 4096;

        if (kk + 1 < KSTEPS) {
            // issue next B tile: contiguous 64KB of granule-major Wt -> linear LDS
            const unsigned short* bsrc = Wt + (size_t)(kk + 1) * 32768 + (size_t)tid * 8;
            unsigned short* bdst = BlS + nxt * 32768 + tid * 8;
            #pragma unroll
            for (int j = 0; j < 8; ++j)
                gload16(bsrc + (size_t)j * 4096, bdst + j * 4096);
            if (tid < 256) {   // issue next A loads early (write after MFMA)
                const float* ap = Abase + (size_t)arow * EDIM + (kk + 1) * BK + ag * 8;
                a0n = *(const float4*)ap;
                a1n = *(const float4*)(ap + 4);
            }
        }

        #pragma unroll
        for (int ks = 0; ks < 2; ++ks) {
            const int g = 2 * ks + hi;
            bf16x8 afr0 = *(const bf16x8*)(Acur + a_addr(l31, g));
            bf16x8 afr1 = *(const bf16x8*)(Acur + a_addr(32 + l31, g));
            #pragma unroll
            for (int nj = 0; nj < 4; ++nj) {
                bf16x8 bfr = *(const bf16x8*)(Bcur +
                    ((size_t)g * 8192 + (size_t)(wid * 128 + nj * 32 + l31) * 8));
                acc[0][nj] = __builtin_amdgcn_mfma_f32_32x32x16_bf16(
                    afr0, bfr, acc[0][nj], 0, 0, 0);
                acc[1][nj] = __builtin_amdgcn_mfma_f32_32x32x16_bf16(
                    afr1, bfr, acc[1][nj], 0, 0, 0);
            }
        }

        if (kk + 1 < KSTEPS && tid < 256)
            *(uint4*)(AlB + nxt * 4096 + a_addr(arow, ag)) = pack8(a0n, a1n);
        __syncthreads();
    }

    // epilogue: + dec_proj + cov*W_c -> tanh -> * v, reduce over H
    float dv[4], wcv[4], vvv[4];
    #pragma unroll
    for (int nj = 0; nj < 4; ++nj) {
        const int h = wid * 128 + nj * 32 + l31;
        dv[nj]  = dp[b * HID + h];
        wcv[nj] = Wc[h];
        vvv[nj] = vv[h];
    }
    #pragma unroll
    for (int mi = 0; mi < 2; ++mi) {
        #pragma unroll
        for (int r = 0; r < 16; ++r) {
            const int row = mi * 32 + (r & 3) + 8 * (r >> 2) + 4 * hi;
            const float cv = cov_s[row];
            float x = 0.f;
            #pragma unroll
            for (int nj = 0; nj < 4; ++nj) {
                float pre = acc[mi][nj][r] + dv[nj] + cv * wcv[nj];
                float pc = fminf(pre, 20.0f);       // tanh(20)==1 in fp32
                float e2 = __expf(2.0f * pc);
                x = fmaf((e2 - 1.0f) / (e2 + 1.0f), vvv[nj], x);
            }
            x += __shfl_xor(x, 1);
            x += __shfl_xor(x, 2);
            x += __shfl_xor(x, 4);
            x += __shfl_xor(x, 8);
            x += __shfl_xor(x, 16);
            if (l31 == 0) sred[row * 8 + wid] = x;
        }
    }
    __syncthreads();
    if (tid < BM) {
        float s = 0.f;
        #pragma unroll
        for (int w = 0; w < 8; ++w) s += sred[tid * 8 + w];
        scores[b * SEQ + s0 + tid] = s;
    }
}

// ---------------- softmax + coverage_new
__global__ void softmax_kernel(const float* __restrict__ scores,
                               const int* __restrict__ mask,
                               const float* __restrict__ cov,
                               float* __restrict__ out)
{
    __shared__ float red[8];
    int b = blockIdx.x, tid = threadIdx.x;   // 256 threads
    float vals[8];
    float mx = -1e30f;
    #pragma unroll
    for (int i = 0; i < 8; ++i) {
        int s = tid + i * 256;
        float sc = scores[b * SEQ + s];
        sc = (mask[b * SEQ + s] == 0) ? -10000.0f : sc;
        vals[i] = sc;
        mx = fmaxf(mx, sc);
    }
    for (int m = 1; m < 64; m <<= 1) mx = fmaxf(mx, __shfl_xor(mx, m));
    if ((tid & 63) == 0) red[tid >> 6] = mx;
    __syncthreads();
    mx = fmaxf(fmaxf(red[0], red[1]), fmaxf(red[2], red[3]));
    float sum = 0.f;
    #pragma unroll
    for (int i = 0; i < 8; ++i) { vals[i] = __expf(vals[i] - mx); sum += vals[i]; }
    for (int m = 1; m < 64; m <<= 1) sum += __shfl_xor(sum, m);
    if ((tid & 63) == 0) red[4 + (tid >> 6)] = sum;
    __syncthreads();
    sum = red[4] + red[5] + red[6] + red[7];
    float inv = 1.0f / sum;
    float* attn = out + BATCH * EDIM;          // after context
    float* covn = attn + BATCH * SEQ;
    #pragma unroll
    for (int i = 0; i < 8; ++i) {
        int s = tid + i * 256;
        float w = vals[i] * inv;
        attn[b * SEQ + s] = w;
        covn[b * SEQ + s] = cov[b * SEQ + s] + w;
    }
}

// ---------------- context = attn @ encoder_outputs  (streaming, 1 GiB read)
__global__ void context_kernel(const float* __restrict__ enc,
                               const float* __restrict__ attn,
                               float* __restrict__ ctx)
{
    __shared__ float w_s[SEQ];
    int b  = blockIdx.x >> 3;
    int e0 = (blockIdx.x & 7) * 256;
    int tid = threadIdx.x;
    for (int i = tid; i < SEQ; i += 256) w_s[i] = attn[b * SEQ + i];
    __syncthreads();
    const float* ep = enc + (size_t)b * SEQ * EDIM + e0 + tid;
    float acc = 0.f;
    #pragma unroll 8
    for (int s = 0; s < SEQ; ++s) acc = fmaf(w_s[s], ep[(size_t)s * EDIM], acc);
    ctx[b * EDIM + e0 + tid] = acc;
}

extern "C" void kernel_launch(void* const* d_in, const int* in_sizes, int n_in,
                              void* d_out, int out_size, void* d_ws, size_t ws_size,
                              hipStream_t stream) {
    const float* dec  = (const float*)d_in[0];
    const float* enc  = (const float*)d_in[1];
    const float* cov  = (const float*)d_in[2];
    const int*   mask = (const int*)d_in[3];
    const float* Wh   = (const float*)d_in[4];
    const float* Wd   = (const float*)d_in[5];
    const float* Wc   = (const float*)d_in[6];
    const float* v    = (const float*)d_in[7];
    float* out = (float*)d_out;

    unsigned short* Wt = (unsigned short*)d_ws;                        // 4 MiB bf16
    float* dp     = (float*)((char*)d_ws + (size_t)HID * EDIM * 2);    // 256 KiB
    float* scores = dp + BATCH * HID;                                  // 512 KiB

    (void)hipFuncSetAttribute((const void*)scores_kernel,
                              hipFuncAttributeMaxDynamicSharedMemorySize, SMEM_BYTES);

    wh_transpose_kernel<<<dim3(64 * 32), dim3(256), 0, stream>>>(Wh, Wt);
    dec_proj_kernel<<<dim3(BATCH * HID / 256), dim3(256), 0, stream>>>(dec, Wd, dp);
    scores_kernel<<<dim3(BATCH * (SEQ / BM)), dim3(512), SMEM_BYTES, stream>>>(
        enc, cov, Wt, dp, Wc, v, scores);
    softmax_kernel<<<dim3(BATCH), dim3(256), 0, stream>>>(scores, mask, cov, out);
    context_kernel<<<dim3(BATCH * (EDIM / 256)), dim3(256), 0, stream>>>(enc, out + BATCH * EDIM, out);
}

// Round 4
// 1140.774 us; speedup vs baseline: 1.0163x; 1.0163x over previous
//
#include <hip/hip_runtime.h>
#include <hip/hip_bf16.h>
#include <stdint.h>

#define BATCH 64
#define SEQ   2048
#define HID   1024
#define EDIM  2048   // 2*HID

#define BM 128        // rows per block
#define BN 512        // cols per block (N-split = 2)
#define BK 32
#define KSTEPS (EDIM / BK)   // 64
// LDS: B 2x32KB + A 2x8KB + cov 512B + sred 2KB
#define SMEM_BYTES (65536 + 16384 + 512 + 2048)

typedef __bf16 bf16x8 __attribute__((ext_vector_type(8)));
typedef float  f32x16 __attribute__((ext_vector_type(16)));
typedef float  f32x4v __attribute__((ext_vector_type(4)));

__device__ __forceinline__ unsigned short f2bf(float x) {
    __hip_bfloat16 h = __float2bfloat16(x);
    return __builtin_bit_cast(unsigned short, h);
}

__device__ __forceinline__ uint4 pack8(f32x4v f0, f32x4v f1) {
    uint4 r;
    r.x = (unsigned)f2bf(f0.x) | ((unsigned)f2bf(f0.y) << 16);
    r.y = (unsigned)f2bf(f0.z) | ((unsigned)f2bf(f0.w) << 16);
    r.z = (unsigned)f2bf(f1.x) | ((unsigned)f2bf(f1.y) << 16);
    r.w = (unsigned)f2bf(f1.z) | ((unsigned)f2bf(f1.w) << 16);
    return r;
}

__device__ __forceinline__ void gload16(const void* g, void* l) {
    __builtin_amdgcn_global_load_lds(
        (const __attribute__((address_space(1))) void*)g,
        (__attribute__((address_space(3))) void*)l, 16, 0, 0);
}

__device__ __forceinline__ f32x4v ntload4(const float* p) {
    return __builtin_nontemporal_load((const f32x4v*)p);
}

// A-tile byte address: row-major 64B rows, XOR swizzle -> conflict-free b128 reads
__device__ __forceinline__ int a_addr(int row, int g) {
    return ((row << 6) + (g << 4)) ^ ((row & 7) << 4);
}

// ---------------- prep: W_h (EDIM x HID fp32) -> Wt bf16, layout:
// element (h,e) at Wt[(e>>3)*8192 + (h>>9)*4096 + (h&511)*8 + (e&7)]
// => per (k-granule, n-half): 4096 contiguous shorts (8KB)
__global__ void wh_transpose_kernel(const float* __restrict__ Wh,
                                    unsigned short* __restrict__ Wt) {
    __shared__ float tile[32][33];
    int bx = blockIdx.x & 63;    // e-tile
    int by = blockIdx.x >> 6;    // h-tile
    int e0 = bx * 32, h0 = by * 32;
    int tx = threadIdx.x & 31, ty = threadIdx.x >> 5;   // 32 x 8
    #pragma unroll
    for (int i = 0; i < 4; ++i)
        tile[ty + 8 * i][tx] = Wh[(size_t)(e0 + ty + 8 * i) * HID + h0 + tx];
    __syncthreads();
    if (ty < 4) {
        uint4 wv;
        unsigned short* ws = (unsigned short*)&wv;
        #pragma unroll
        for (int j = 0; j < 8; ++j) ws[j] = f2bf(tile[ty * 8 + j][tx]);
        int h = h0 + tx;
        *(uint4*)&Wt[(size_t)((e0 >> 3) + ty) * 8192 + (h >> 9) * 4096 + (h & 511) * 8] = wv;
    }
}

// ---------------- prep: dec_proj = decoder_hidden @ W_d  (fp32, (B,HID))
__global__ void dec_proj_kernel(const float* __restrict__ dec,
                                const float* __restrict__ Wd,
                                float* __restrict__ dp) {
    int gid = blockIdx.x * 256 + threadIdx.x;
    int b = gid >> 10, h = gid & 1023;
    const float* dr = dec + b * HID;
    float acc = 0.f;
    #pragma unroll 4
    for (int k = 0; k < HID; ++k) acc = fmaf(dr[k], Wd[(size_t)k * HID + h], acc);
    dp[gid] = acc;
}

// ---------------- main fused scores kernel: 128 rows x 512 cols, 8 waves
__global__ __launch_bounds__(512, 2) void scores_kernel(
    const float* __restrict__ enc, const float* __restrict__ cov,
    const unsigned short* __restrict__ Wt, const float* __restrict__ dp,
    const float* __restrict__ Wc, const float* __restrict__ vv,
    float* __restrict__ spart_out)
{
    extern __shared__ char smem[];
    unsigned short* BlS  = (unsigned short*)smem;          // 2 x 16384 shorts (64KB)
    char*  AlB   = smem + 65536;                           // 2 x 8192 B
    float* cov_s = (float*)(smem + 81920);                 // 128 floats
    float* sred  = (float*)(smem + 82432);                 // 128 x 4 floats

    const int tid  = threadIdx.x;
    const int lane = tid & 63;
    const int wid  = tid >> 6;       // 0..7
    const int wm   = wid >> 2;       // 0..1 : 64-row half
    const int wn   = wid & 3;        // 0..3 : 128-col slice
    const int l31  = lane & 31;
    const int hi   = lane >> 5;

    // block -> (m-block, n-half); round-robin XCD heuristic keeps one half per XCD group
    const int bid  = blockIdx.x;
    const int half = (bid & 7) >> 2;
    const int m    = ((bid >> 3) << 2) | (bid & 3);   // 0..1023
    const int b    = m >> 4;
    const int s0   = (m & 15) * BM;

    const float* Abase = enc + (size_t)(b * SEQ + s0) * EDIM;

    // A staging: 512 threads, one k-granule (8 fp32 -> 16B bf16) each
    const int arow = tid >> 2;                 // 0..127
    const int ag   = tid & 3;

    f32x16 acc[2][4];
    #pragma unroll
    for (int mi = 0; mi < 2; ++mi)
        #pragma unroll
        for (int nj = 0; nj < 4; ++nj)
            #pragma unroll
            for (int r = 0; r < 16; ++r) acc[mi][nj][r] = 0.f;

    if (tid < BM) cov_s[tid] = cov[b * SEQ + s0 + tid];

    // prologue: stage k-step 0 into buffer 0
    {
        const unsigned short* bsrc = Wt + half * 4096 + (size_t)tid * 8;
        unsigned short* bdst = BlS + tid * 8;
        #pragma unroll
        for (int j = 0; j < 4; ++j)
            gload16(bsrc + (size_t)j * 8192, bdst + j * 4096);
        const float* ap = Abase + (size_t)arow * EDIM + ag * 8;
        *(uint4*)(AlB + a_addr(arow, ag)) = pack8(ntload4(ap), ntload4(ap + 4));
    }
    __syncthreads();

    f32x4v a0n, a1n;
    for (int kk = 0; kk < KSTEPS; ++kk) {
        const int cur = kk & 1, nxt = cur ^ 1;
        const unsigned short* Bcur = BlS + cur * 16384;
        const char* Acur = AlB + cur * 8192;

        if (kk + 1 < KSTEPS) {
            // issue next B tile: 4 x 8KB contiguous chunks of Wt -> linear LDS
            const unsigned short* bsrc =
                Wt + (size_t)(kk + 1) * 32768 + half * 4096 + (size_t)tid * 8;
            unsigned short* bdst = BlS + nxt * 16384 + tid * 8;
            #pragma unroll
            for (int j = 0; j < 4; ++j)
                gload16(bsrc + (size_t)j * 8192, bdst + j * 4096);
            // issue next A loads early (nontemporal: keep enc out of L2)
            const float* ap = Abase + (size_t)arow * EDIM + (kk + 1) * BK + ag * 8;
            a0n = ntload4(ap);
            a1n = ntload4(ap + 4);
        }

        #pragma unroll
        for (int ks = 0; ks < 2; ++ks) {
            const int g = 2 * ks + hi;
            bf16x8 afr0 = *(const bf16x8*)(Acur + a_addr(wm * 64 + l31, g));
            bf16x8 afr1 = *(const bf16x8*)(Acur + a_addr(wm * 64 + 32 + l31, g));
            #pragma unroll
            for (int nj = 0; nj < 4; ++nj) {
                bf16x8 bfr = *(const bf16x8*)(Bcur +
                    (size_t)g * 4096 + (size_t)(wn * 128 + nj * 32 + l31) * 8);
                acc[0][nj] = __builtin_amdgcn_mfma_f32_32x32x16_bf16(
                    afr0, bfr, acc[0][nj], 0, 0, 0);
                acc[1][nj] = __builtin_amdgcn_mfma_f32_32x32x16_bf16(
                    afr1, bfr, acc[1][nj], 0, 0, 0);
            }
        }

        if (kk + 1 < KSTEPS)
            *(uint4*)(AlB + nxt * 8192 + a_addr(arow, ag)) = pack8(a0n, a1n);
        __syncthreads();
    }

    // epilogue: + dec_proj + cov*W_c -> tanh -> * v, reduce over this block's 512 cols
    float dv[4], wcv[4], vvv[4];
    #pragma unroll
    for (int nj = 0; nj < 4; ++nj) {
        const int h = half * BN + wn * 128 + nj * 32 + l31;
        dv[nj]  = dp[b * HID + h];
        wcv[nj] = Wc[h];
        vvv[nj] = vv[h];
    }
    #pragma unroll
    for (int mi = 0; mi < 2; ++mi) {
        #pragma unroll
        for (int r = 0; r < 16; ++r) {
            const int row = wm * 64 + mi * 32 + (r & 3) + 8 * (r >> 2) + 4 * hi;
            const float cv = cov_s[row];
            float x = 0.f;
            #pragma unroll
            for (int nj = 0; nj < 4; ++nj) {
                float pre = acc[mi][nj][r] + dv[nj] + cv * wcv[nj];
                float pc = fminf(pre, 20.0f);       // tanh(20)==1 in fp32
                float e2 = __expf(2.0f * pc);
                x = fmaf((e2 - 1.0f) / (e2 + 1.0f), vvv[nj], x);
            }
            x += __shfl_xor(x, 1);
            x += __shfl_xor(x, 2);
            x += __shfl_xor(x, 4);
            x += __shfl_xor(x, 8);
            x += __shfl_xor(x, 16);
            if (l31 == 0) sred[row * 4 + wn] = x;
        }
    }
    __syncthreads();
    if (tid < BM) {
        float s = sred[tid * 4] + sred[tid * 4 + 1] + sred[tid * 4 + 2] + sred[tid * 4 + 3];
        spart_out[(size_t)half * BATCH * SEQ + b * SEQ + s0 + tid] = s;
    }
}

// ---------------- softmax + coverage_new (sums the two N-half partial scores)
__global__ void softmax_kernel(const float* __restrict__ spart,
                               const int* __restrict__ mask,
                               const float* __restrict__ cov,
                               float* __restrict__ out)
{
    __shared__ float red[8];
    int b = blockIdx.x, tid = threadIdx.x;   // 256 threads
    float vals[8];
    float mx = -1e30f;
    #pragma unroll
    for (int i = 0; i < 8; ++i) {
        int s = tid + i * 256;
        float sc = spart[b * SEQ + s] + spart[BATCH * SEQ + b * SEQ + s];
        sc = (mask[b * SEQ + s] == 0) ? -10000.0f : sc;
        vals[i] = sc;
        mx = fmaxf(mx, sc);
    }
    for (int m = 1; m < 64; m <<= 1) mx = fmaxf(mx, __shfl_xor(mx, m));
    if ((tid & 63) == 0) red[tid >> 6] = mx;
    __syncthreads();
    mx = fmaxf(fmaxf(red[0], red[1]), fmaxf(red[2], red[3]));
    float sum = 0.f;
    #pragma unroll
    for (int i = 0; i < 8; ++i) { vals[i] = __expf(vals[i] - mx); sum += vals[i]; }
    for (int m = 1; m < 64; m <<= 1) sum += __shfl_xor(sum, m);
    if ((tid & 63) == 0) red[4 + (tid >> 6)] = sum;
    __syncthreads();
    sum = red[4] + red[5] + red[6] + red[7];
    float inv = 1.0f / sum;
    float* attn = out + BATCH * EDIM;
    float* covn = attn + BATCH * SEQ;
    #pragma unroll
    for (int i = 0; i < 8; ++i) {
        int s = tid + i * 256;
        float w = vals[i] * inv;
        attn[b * SEQ + s] = w;
        covn[b * SEQ + s] = cov[b * SEQ + s] + w;
    }
}

// ---------------- context = attn @ encoder_outputs  (streaming, 1 GiB read)
__global__ void context_kernel(const float* __restrict__ enc,
                               const float* __restrict__ attn,
                               float* __restrict__ ctx)
{
    __shared__ float w_s[SEQ];
    int b  = blockIdx.x >> 3;
    int e0 = (blockIdx.x & 7) * 256;
    int tid = threadIdx.x;
    for (int i = tid; i < SEQ; i += 256) w_s[i] = attn[b * SEQ + i];
    __syncthreads();
    const float* ep = enc + (size_t)b * SEQ * EDIM + e0 + tid;
    float acc = 0.f;
    #pragma unroll 8
    for (int s = 0; s < SEQ; ++s)
        acc = fmaf(w_s[s], __builtin_nontemporal_load(ep + (size_t)s * EDIM), acc);
    ctx[b * EDIM + e0 + tid] = acc;
}

extern "C" void kernel_launch(void* const* d_in, const int* in_sizes, int n_in,
                              void* d_out, int out_size, void* d_ws, size_t ws_size,
                              hipStream_t stream) {
    const float* dec  = (const float*)d_in[0];
    const float* enc  = (const float*)d_in[1];
    const float* cov  = (const float*)d_in[2];
    const int*   mask = (const int*)d_in[3];
    const float* Wh   = (const float*)d_in[4];
    const float* Wd   = (const float*)d_in[5];
    const float* Wc   = (const float*)d_in[6];
    const float* v    = (const float*)d_in[7];
    float* out = (float*)d_out;

    unsigned short* Wt = (unsigned short*)d_ws;                        // 4 MiB bf16
    float* dp    = (float*)((char*)d_ws + (size_t)HID * EDIM * 2);     // 256 KiB
    float* spart = dp + BATCH * HID;                                   // 1 MiB (2 halves)

    (void)hipFuncSetAttribute((const void*)scores_kernel,
                              hipFuncAttributeMaxDynamicSharedMemorySize, SMEM_BYTES);

    wh_transpose_kernel<<<dim3(64 * 32), dim3(256), 0, stream>>>(Wh, Wt);
    dec_proj_kernel<<<dim3(BATCH * HID / 256), dim3(256), 0, stream>>>(dec, Wd, dp);
    scores_kernel<<<dim3((SEQ * BATCH / BM) * 2), dim3(512), SMEM_BYTES, stream>>>(
        enc, cov, Wt, dp, Wc, v, spart);
    softmax_kernel<<<dim3(BATCH), dim3(256), 0, stream>>>(spart, mask, cov, out);
    context_kernel<<<dim3(BATCH * (EDIM / 256)), dim3(256), 0, stream>>>(enc, out + BATCH * EDIM, out);
}

// Round 5
// 1134.191 us; speedup vs baseline: 1.0222x; 1.0058x over previous
//
#include <hip/hip_runtime.h>
#include <hip/hip_bf16.h>
#include <stdint.h>

#define BATCH 64
#define SEQ   2048
#define HID   1024
#define EDIM  2048   // 2*HID

#define BM 128        // rows per block
#define BN 512        // cols per block (N-split = 2)
#define BK 32
#define KSTEPS (EDIM / BK)   // 64
// LDS: B ring 4x32KB + A dbuf 2x8KB + cov 512B + sred 2KB
#define SMEM_BYTES 150016

typedef __bf16 bf16x8 __attribute__((ext_vector_type(8)));
typedef float  f32x16 __attribute__((ext_vector_type(16)));
typedef float  f32x4v __attribute__((ext_vector_type(4)));

__device__ __forceinline__ unsigned short f2bf(float x) {
    __hip_bfloat16 h = __float2bfloat16(x);
    return __builtin_bit_cast(unsigned short, h);
}

__device__ __forceinline__ uint4 pack8(f32x4v f0, f32x4v f1) {
    uint4 r;
    r.x = (unsigned)f2bf(f0.x) | ((unsigned)f2bf(f0.y) << 16);
    r.y = (unsigned)f2bf(f0.z) | ((unsigned)f2bf(f0.w) << 16);
    r.z = (unsigned)f2bf(f1.x) | ((unsigned)f2bf(f1.y) << 16);
    r.w = (unsigned)f2bf(f1.z) | ((unsigned)f2bf(f1.w) << 16);
    return r;
}

__device__ __forceinline__ void gload16(const void* g, void* l) {
    __builtin_amdgcn_global_load_lds(
        (const __attribute__((address_space(1))) void*)g,
        (__attribute__((address_space(3))) void*)l, 16, 0, 0);
}

__device__ __forceinline__ f32x4v ntload4(const float* p) {
    return __builtin_nontemporal_load((const f32x4v*)p);
}

// A-tile byte address: row-major 64B rows, XOR swizzle -> conflict-free b128 reads
__device__ __forceinline__ int a_addr(int row, int g) {
    return ((row << 6) + (g << 4)) ^ ((row & 7) << 4);
}

// ---------------- prep: W_h (EDIM x HID fp32) -> Wt bf16, layout:
// element (h,e) at Wt[(e>>3)*8192 + (h>>9)*4096 + (h&511)*8 + (e&7)]
__global__ void wh_transpose_kernel(const float* __restrict__ Wh,
                                    unsigned short* __restrict__ Wt) {
    __shared__ float tile[32][33];
    int bx = blockIdx.x & 63;    // e-tile
    int by = blockIdx.x >> 6;    // h-tile
    int e0 = bx * 32, h0 = by * 32;
    int tx = threadIdx.x & 31, ty = threadIdx.x >> 5;   // 32 x 8
    #pragma unroll
    for (int i = 0; i < 4; ++i)
        tile[ty + 8 * i][tx] = Wh[(size_t)(e0 + ty + 8 * i) * HID + h0 + tx];
    __syncthreads();
    if (ty < 4) {
        uint4 wv;
        unsigned short* ws = (unsigned short*)&wv;
        #pragma unroll
        for (int j = 0; j < 8; ++j) ws[j] = f2bf(tile[ty * 8 + j][tx]);
        int h = h0 + tx;
        *(uint4*)&Wt[(size_t)((e0 >> 3) + ty) * 8192 + (h >> 9) * 4096 + (h & 511) * 8] = wv;
    }
}

// ---------------- prep: dec_proj = decoder_hidden @ W_d  (fp32, (B,HID))
__global__ void dec_proj_kernel(const float* __restrict__ dec,
                                const float* __restrict__ Wd,
                                float* __restrict__ dp) {
    int gid = blockIdx.x * 256 + threadIdx.x;
    int b = gid >> 10, h = gid & 1023;
    const float* dr = dec + b * HID;
    float acc = 0.f;
    #pragma unroll 4
    for (int k = 0; k < HID; ++k) acc = fmaf(dr[k], Wd[(size_t)k * HID + h], acc);
    dp[gid] = acc;
}

#define MFMA32(a, bfv, c) __builtin_amdgcn_mfma_f32_32x32x16_bf16(a, bfv, c, 0, 0, 0)

// ---------------- main fused scores kernel: 128 rows x 512 cols, 8 waves,
// counted-vmcnt deep pipeline (B 2 k-steps ahead in a 4-slot LDS ring)
__global__ __launch_bounds__(512, 2) void scores_kernel(
    const float* __restrict__ enc, const float* __restrict__ cov,
    const unsigned short* __restrict__ Wt, const float* __restrict__ dp,
    const float* __restrict__ Wc, const float* __restrict__ vv,
    float* __restrict__ spart_out)
{
    extern __shared__ char smem[];
    unsigned short* BlS = (unsigned short*)smem;        // 4 slots x 16384 shorts
    char*  AlB   = smem + 131072;                       // 2 x 8192 B
    float* cov_s = (float*)(smem + 147456);             // 128 floats
    float* sred  = (float*)(smem + 147968);             // 128 x 4 floats

    const int tid  = threadIdx.x;
    const int lane = tid & 63;
    const int wid  = tid >> 6;       // 0..7
    const int wm   = wid >> 2;       // 0..1 : 64-row half
    const int wn   = wid & 3;        // 0..3 : 128-col slice
    const int l31  = lane & 31;
    const int hi   = lane >> 5;

    const int bid  = blockIdx.x;
    const int half = (bid & 7) >> 2;
    const int m    = ((bid >> 3) << 2) | (bid & 3);
    const int b    = m >> 4;
    const int s0   = (m & 15) * BM;

    const float* Abase = enc + (size_t)(b * SEQ + s0) * EDIM;
    const int arow = tid >> 2;                 // 0..127
    const int ag   = tid & 3;

    const unsigned short* Bsrc0 = Wt + half * 4096 + (size_t)tid * 8;

    f32x16 acc[2][4];
    #pragma unroll
    for (int mi = 0; mi < 2; ++mi)
        #pragma unroll
        for (int nj = 0; nj < 4; ++nj)
            #pragma unroll
            for (int r = 0; r < 16; ++r) acc[mi][nj][r] = 0.f;

    f32x4v aL0[2], aL1[2];

    // ---- prologue: A(0)+B(0), write A(0); A(1)+B(1); counted drain; barrier
    {
        const float* ap = Abase + (size_t)arow * EDIM + ag * 8;
        aL0[0] = ntload4(ap); aL1[0] = ntload4(ap + 4);
    }
    #pragma unroll
    for (int j = 0; j < 4; ++j)
        gload16(Bsrc0 + (size_t)j * 8192, BlS + j * 4096 + tid * 8);
    asm volatile("s_waitcnt vmcnt(4)" ::: "memory");
    *(uint4*)(AlB + a_addr(arow, ag)) = pack8(aL0[0], aL1[0]);
    {
        const float* ap = Abase + (size_t)arow * EDIM + BK + ag * 8;
        aL0[1] = ntload4(ap); aL1[1] = ntload4(ap + 4);
    }
    #pragma unroll
    for (int j = 0; j < 4; ++j)
        gload16(Bsrc0 + (size_t)(4 + j) * 8192, BlS + 16384 + j * 4096 + tid * 8);
    asm volatile("s_waitcnt vmcnt(6) lgkmcnt(0)" ::: "memory");
    __builtin_amdgcn_s_barrier();

    // ---- main loop, unroll x4 so ring slot (u) and A-set (u&1) are compile-time
    for (int kk4 = 0; kk4 < KSTEPS; kk4 += 4) {
        #pragma unroll
        for (int u = 0; u < 4; ++u) {
            const int kk = kk4 + u;
            if (kk + 2 < KSTEPS) {
                // issue A(kk+2) reg loads (set u&1), then B(kk+2) gloads (slot (u+2)&3)
                const float* ap = Abase + (size_t)arow * EDIM + (kk + 2) * BK + ag * 8;
                aL0[u & 1] = ntload4(ap); aL1[u & 1] = ntload4(ap + 4);
                const unsigned short* bs = Bsrc0 + (size_t)(kk + 2) * 32768;
                unsigned short* bd = BlS + ((u + 2) & 3) * 16384 + tid * 8;
                #pragma unroll
                for (int j = 0; j < 4; ++j)
                    gload16(bs + (size_t)j * 8192, bd + j * 4096);
            }
            const unsigned short* Bcur = BlS + u * 16384;
            const char* Acur = AlB + (u & 1) * 8192;

            bf16x8 afr[2][2], bfr[2][4];
            #pragma unroll
            for (int ks = 0; ks < 2; ++ks) {
                const int g = 2 * ks + hi;
                afr[ks][0] = *(const bf16x8*)(Acur + a_addr(wm * 64 + l31, g));
                afr[ks][1] = *(const bf16x8*)(Acur + a_addr(wm * 64 + 32 + l31, g));
                #pragma unroll
                for (int nj = 0; nj < 4; ++nj)
                    bfr[ks][nj] = *(const bf16x8*)(Bcur +
                        (size_t)g * 4096 + (size_t)(wn * 128 + nj * 32 + l31) * 8);
            }
            asm volatile("s_waitcnt lgkmcnt(6)" ::: "memory");
            __builtin_amdgcn_sched_barrier(0);
            __builtin_amdgcn_s_setprio(1);
            #pragma unroll
            for (int nj = 0; nj < 4; ++nj) {
                acc[0][nj] = MFMA32(afr[0][0], bfr[0][nj], acc[0][nj]);
                acc[1][nj] = MFMA32(afr[0][1], bfr[0][nj], acc[1][nj]);
            }
            __builtin_amdgcn_s_setprio(0);
            asm volatile("s_waitcnt lgkmcnt(0)" ::: "memory");
            __builtin_amdgcn_sched_barrier(0);
            __builtin_amdgcn_s_setprio(1);
            #pragma unroll
            for (int nj = 0; nj < 4; ++nj) {
                acc[0][nj] = MFMA32(afr[1][0], bfr[1][nj], acc[0][nj]);
                acc[1][nj] = MFMA32(afr[1][1], bfr[1][nj], acc[1][nj]);
            }
            __builtin_amdgcn_s_setprio(0);

            // write A(kk+1) (loaded last iter) into buf (u+1)&1; compiler inserts
            // the minimal vmcnt for the reg dep
            if (kk + 1 < KSTEPS)
                *(uint4*)(AlB + ((u + 1) & 1) * 8192 + a_addr(arow, ag)) =
                    pack8(aL0[(u + 1) & 1], aL1[(u + 1) & 1]);

            // counted drain: keep this iter's 6 issues in flight, retire older
            if (kk + 2 < KSTEPS)
                asm volatile("s_waitcnt vmcnt(6) lgkmcnt(0)" ::: "memory");
            else
                asm volatile("s_waitcnt vmcnt(0) lgkmcnt(0)" ::: "memory");
            __builtin_amdgcn_s_barrier();
        }
    }

    // ---- epilogue (all global loads kept out of the pipelined loop)
    if (tid < BM) cov_s[tid] = cov[b * SEQ + s0 + tid];
    __syncthreads();

    float dv[4], wcv[4], vvv[4];
    #pragma unroll
    for (int nj = 0; nj < 4; ++nj) {
        const int h = half * BN + wn * 128 + nj * 32 + l31;
        dv[nj]  = dp[b * HID + h];
        wcv[nj] = Wc[h];
        vvv[nj] = vv[h];
    }
    #pragma unroll
    for (int mi = 0; mi < 2; ++mi) {
        #pragma unroll
        for (int r = 0; r < 16; ++r) {
            const int row = wm * 64 + mi * 32 + (r & 3) + 8 * (r >> 2) + 4 * hi;
            const float cv = cov_s[row];
            float x = 0.f;
            #pragma unroll
            for (int nj = 0; nj < 4; ++nj) {
                float pre = acc[mi][nj][r] + dv[nj] + cv * wcv[nj];
                float pc = fminf(pre, 20.0f);       // tanh(20)==1 in fp32
                float e2 = __expf(2.0f * pc);
                x = fmaf((e2 - 1.0f) / (e2 + 1.0f), vvv[nj], x);
            }
            x += __shfl_xor(x, 1);
            x += __shfl_xor(x, 2);
            x += __shfl_xor(x, 4);
            x += __shfl_xor(x, 8);
            x += __shfl_xor(x, 16);
            if (l31 == 0) sred[row * 4 + wn] = x;
        }
    }
    __syncthreads();
    if (tid < BM) {
        float s = sred[tid * 4] + sred[tid * 4 + 1] + sred[tid * 4 + 2] + sred[tid * 4 + 3];
        spart_out[(size_t)half * BATCH * SEQ + b * SEQ + s0 + tid] = s;
    }
}

// ---------------- softmax + coverage_new (sums the two N-half partial scores)
__global__ void softmax_kernel(const float* __restrict__ spart,
                               const int* __restrict__ mask,
                               const float* __restrict__ cov,
                               float* __restrict__ out)
{
    __shared__ float red[8];
    int b = blockIdx.x, tid = threadIdx.x;   // 256 threads
    float vals[8];
    float mx = -1e30f;
    #pragma unroll
    for (int i = 0; i < 8; ++i) {
        int s = tid + i * 256;
        float sc = spart[b * SEQ + s] + spart[BATCH * SEQ + b * SEQ + s];
        sc = (mask[b * SEQ + s] == 0) ? -10000.0f : sc;
        vals[i] = sc;
        mx = fmaxf(mx, sc);
    }
    for (int m = 1; m < 64; m <<= 1) mx = fmaxf(mx, __shfl_xor(mx, m));
    if ((tid & 63) == 0) red[tid >> 6] = mx;
    __syncthreads();
    mx = fmaxf(fmaxf(red[0], red[1]), fmaxf(red[2], red[3]));
    float sum = 0.f;
    #pragma unroll
    for (int i = 0; i < 8; ++i) { vals[i] = __expf(vals[i] - mx); sum += vals[i]; }
    for (int m = 1; m < 64; m <<= 1) sum += __shfl_xor(sum, m);
    if ((tid & 63) == 0) red[4 + (tid >> 6)] = sum;
    __syncthreads();
    sum = red[4] + red[5] + red[6] + red[7];
    float inv = 1.0f / sum;
    float* attn = out + BATCH * EDIM;
    float* covn = attn + BATCH * SEQ;
    #pragma unroll
    for (int i = 0; i < 8; ++i) {
        int s = tid + i * 256;
        float w = vals[i] * inv;
        attn[b * SEQ + s] = w;
        covn[b * SEQ + s] = cov[b * SEQ + s] + w;
    }
}

// ---------------- context = attn @ encoder_outputs  (streaming, 1 GiB read)
__global__ void context_kernel(const float* __restrict__ enc,
                               const float* __restrict__ attn,
                               float* __restrict__ ctx)
{
    __shared__ float w_s[SEQ];
    int b  = blockIdx.x >> 3;
    int e0 = (blockIdx.x & 7) * 256;
    int tid = threadIdx.x;
    for (int i = tid; i < SEQ; i += 256) w_s[i] = attn[b * SEQ + i];
    __syncthreads();
    const float* ep = enc + (size_t)b * SEQ * EDIM + e0 + tid;
    float acc = 0.f;
    #pragma unroll 8
    for (int s = 0; s < SEQ; ++s)
        acc = fmaf(w_s[s], __builtin_nontemporal_load(ep + (size_t)s * EDIM), acc);
    ctx[b * EDIM + e0 + tid] = acc;
}

extern "C" void kernel_launch(void* const* d_in, const int* in_sizes, int n_in,
                              void* d_out, int out_size, void* d_ws, size_t ws_size,
                              hipStream_t stream) {
    const float* dec  = (const float*)d_in[0];
    const float* enc  = (const float*)d_in[1];
    const float* cov  = (const float*)d_in[2];
    const int*   mask = (const int*)d_in[3];
    const float* Wh   = (const float*)d_in[4];
    const float* Wd   = (const float*)d_in[5];
    const float* Wc   = (const float*)d_in[6];
    const float* v    = (const float*)d_in[7];
    float* out = (float*)d_out;

    unsigned short* Wt = (unsigned short*)d_ws;                        // 4 MiB bf16
    float* dp    = (float*)((char*)d_ws + (size_t)HID * EDIM * 2);     // 256 KiB
    float* spart = dp + BATCH * HID;                                   // 1 MiB (2 halves)

    (void)hipFuncSetAttribute((const void*)scores_kernel,
                              hipFuncAttributeMaxDynamicSharedMemorySize, SMEM_BYTES);

    wh_transpose_kernel<<<dim3(64 * 32), dim3(256), 0, stream>>>(Wh, Wt);
    dec_proj_kernel<<<dim3(BATCH * HID / 256), dim3(256), 0, stream>>>(dec, Wd, dp);
    scores_kernel<<<dim3((SEQ * BATCH / BM) * 2), dim3(512), SMEM_BYTES, stream>>>(
        enc, cov, Wt, dp, Wc, v, spart);
    softmax_kernel<<<dim3(BATCH), dim3(256), 0, stream>>>(spart, mask, cov, out);
    context_kernel<<<dim3(BATCH * (EDIM / 256)), dim3(256), 0, stream>>>(enc, out + BATCH * EDIM, out);
}